// Round 4
// baseline (103.122 us; speedup 1.0000x reference)
//
#include <hip/hip_runtime.h>
#include <math.h>

using short8 = __attribute__((ext_vector_type(8))) short;
using f32x4v = __attribute__((ext_vector_type(4))) float;

__device__ __forceinline__ short f2bf(float f) {  // fp32 -> bf16 RNE
  unsigned u = __builtin_bit_cast(unsigned, f);
  unsigned r = (u + 0x7fffu + ((u >> 16) & 1u)) >> 16;
  return (short)r;
}

// ---------------- kp1_desc: bilinear sample of desc1 at kp1 (exact fp32) ----
__global__ void kpd_kernel(const float* __restrict__ kp1,
                           const float* __restrict__ desc1,
                           float* __restrict__ okpd) {
  int k = blockIdx.x;
  int c = threadIdx.x;
  float b = kp1[k * 4 + 0];
  float y = kp1[k * 4 + 2] * 0.125f;
  float x = kp1[k * 4 + 3] * 0.125f;
  float x0 = fminf(fmaxf(floorf(x), 0.f), 31.f);
  float y0 = fminf(fmaxf(floorf(y), 0.f), 31.f);
  float x1 = fminf(x0 + 1.f, 31.f);
  float y1 = fminf(y0 + 1.f, 31.f);
  float wx = x - x0;
  float wy = y - y0;
  int bi = (int)b;
  const float* dp = desc1 + ((size_t)bi * 128 + c) * 1024;
  int ix0 = (int)x0, ix1 = (int)x1, iy0 = (int)y0, iy1 = (int)y1;
  float d00 = dp[iy0 * 32 + ix0];
  float d01 = dp[iy0 * 32 + ix1];
  float d10 = dp[iy1 * 32 + ix0];
  float d11 = dp[iy1 * 32 + ix1];
  float r = d00 * (1.f - wx) * (1.f - wy) + d01 * wx * (1.f - wy)
          + d10 * (1.f - wx) * wy + d11 * wx * wy;
  okpd[k * 128 + c] = r;
}

// ---------------- prep: vis product + warped grid coords per cell ----------
// grid 64 = (8 seg) x (8 n); thread t<128 handles cell seg*128+t.
__global__ void prep_kernel(const float* __restrict__ vism,
                            const float* __restrict__ homo,
                            float* __restrict__ visg,
                            float* __restrict__ wgx, float* __restrict__ wgy) {
  int n = blockIdx.x & 7;
  int seg = blockIdx.x >> 3;
  int t = threadIdx.x;
  if (t >= 128) return;
  int cell = seg * 128 + t;
  int ph = cell >> 5, pw = cell & 31;
  const float* mrow = vism + ((size_t)n * 256 + ph * 8) * 256 + pw * 8;
  float v = 1.f;
#pragma unroll
  for (int dy = 0; dy < 8; ++dy) {
    const float4* p = (const float4*)(mrow + dy * 256);
    float4 a = p[0], bq = p[1];
    v *= a.x * a.y * a.z * a.w;
    v *= bq.x * bq.y * bq.z * bq.w;
  }
  float gx = (float)(pw * 8 + 4);
  float gy = (float)(ph * 8 + 4);
  float w0 = homo[n * 9 + 0] * gx + homo[n * 9 + 1] * gy + homo[n * 9 + 2];
  float w1 = homo[n * 9 + 3] * gx + homo[n * 9 + 4] * gy + homo[n * 9 + 5];
  float w2 = homo[n * 9 + 6] * gx + homo[n * 9 + 7] * gy + homo[n * 9 + 8];
  visg[n * 1024 + cell] = v;
  wgx[n * 1024 + cell] = w0 / w2;
  wgy[n * 1024 + cell] = w1 / w2;
}

// ---------------- lists: active cells per (n, kp) --------------------------
// grid 1024 = (n, kp-group of 8); full-image scan once per (n,kp).
__global__ void list_kernel(const float* __restrict__ kp1,
                            const float* __restrict__ wgx,
                            const float* __restrict__ wgy,
                            int* __restrict__ cntw, int* __restrict__ cellw) {
  __shared__ int cnt8[8];
  __shared__ int cells8[64];
  __shared__ float kx[8], ky[8];
  int t = threadIdx.x;
  int n = blockIdx.x & 7;
  int kp0 = (blockIdx.x >> 3) * 8;
  if (t < 8) {
    cnt8[t] = 0;
    kx[t] = kp1[(kp0 + t) * 4 + 3];
    ky[t] = kp1[(kp0 + t) * 4 + 2];
  }
  if (t < 64) cells8[t] = 0;
  __syncthreads();
#pragma unroll
  for (int i = 0; i < 4; ++i) {
    int cell = t + 256 * i;
    float wx_ = wgx[n * 1024 + cell];
    float wy_ = wgy[n * 1024 + cell];
#pragma unroll
    for (int kt = 0; kt < 8; ++kt) {
      float dx = kx[kt] - wx_;
      float dy = ky[kt] - wy_;
      float d2 = dx * dx + dy * dy;
      if (d2 <= 56.25f) {
        int pos = atomicAdd(&cnt8[kt], 1);
        if (pos < 8) cells8[kt * 8 + pos] = cell;
      }
    }
  }
  __syncthreads();
  if (t < 8) cntw[n * 1024 + kp0 + t] = min(cnt8[t], 8);
  if (t < 64) cellw[(n * 1024 + kp0) * 8 + t] = cells8[t];
}

// ---------------- main: bf16 MFMA GEMM + fused hinge epilogue ---------------
// block = (n, kp-tile of 64, px-tile of 128); 256 thr = 4 waves, each wave
// 16 kp rows x 128 px cols (8 MFMA tiles, K=128 in 4 steps of 32).
__global__ __launch_bounds__(256, 2) void main_kernel(
    const float* __restrict__ kp1, const float* __restrict__ desc2,
    const float* __restrict__ visg, const float* __restrict__ wgx,
    const float* __restrict__ wgy, const int* __restrict__ cntw,
    const int* __restrict__ cellw, const float* __restrict__ gkpd,
    float* __restrict__ loss_out, float inv31sq, float inv11sq, float inv5sq) {
  __shared__ short sA[64 * 128];    // [kp][c] bf16, octet XOR-swizzled
  __shared__ short sB[128 * 128];   // [px][c] bf16, octet XOR-swizzled
  __shared__ float s_stamp[961];
  __shared__ float s_wx[128], s_wy[128], s_vis[128];
  __shared__ float s_kpx[64], s_kpy[64];
  __shared__ int s_cnt[64];
  __shared__ int s_cells[512];
  __shared__ float s_red[4];

  const int t = threadIdx.x;
  const int bid = blockIdx.x;
  const int n = bid & 7;               // XCD-locality swizzle
  const int rem = bid >> 3;
  const int k0 = (rem & 15) * 64;      // kp tile base
  const int p0 = (rem >> 4) * 128;     // px tile base

  // ---- stage A (kpd) as bf16 [64][128], swizzle byte ^= ((kp&7)<<4) ----
  {
    int kp = t >> 2;
    const float* gsrc = gkpd + (size_t)(k0 + kp) * 128;
#pragma unroll
    for (int i = 0; i < 4; ++i) {
      int oct = (t & 3) * 4 + i;
      const float4* p = (const float4*)(gsrc + oct * 8);
      float4 f0 = p[0], f1 = p[1];
      short8 v;
      v[0] = f2bf(f0.x); v[1] = f2bf(f0.y); v[2] = f2bf(f0.z); v[3] = f2bf(f0.w);
      v[4] = f2bf(f1.x); v[5] = f2bf(f1.y); v[6] = f2bf(f1.z); v[7] = f2bf(f1.w);
      *(short8*)((char*)sA + kp * 256 + ((oct * 16) ^ ((kp & 7) << 4))) = v;
    }
  }
  // ---- stage B (desc2^T) as bf16 [128 px][128 c]; px-coalesced gather ----
  {
    int px = t & 127;
    int h = t >> 7;
    const float* gb = desc2 + (size_t)n * 131072 + p0 + px;
#pragma unroll
    for (int o8 = 0; o8 < 8; ++o8) {
      int oct = h * 8 + o8;
      int c0 = oct * 8;
      short8 v;
#pragma unroll
      for (int j = 0; j < 8; ++j) v[j] = f2bf(gb[(size_t)(c0 + j) * 1024]);
      *(short8*)((char*)sB + px * 256 + ((oct * 16) ^ ((px & 7) << 4))) = v;
    }
  }
  // ---- stamp table + per-tile metadata ----
#pragma unroll
  for (int j = 0; j < 4; ++j) {
    int idx = t + 256 * j;
    if (idx < 961) {
      int dy = idx / 31, dx = idx % 31;
      float ay = (float)(dy - 15), ax = (float)(dx - 15);
      float r2 = ay * ay + ax * ax;
      float v = expf(r2 * (-1.f / 98.f)) * inv31sq;
      if (dy >= 10 && dy <= 20 && dx >= 10 && dx <= 20)
        v += expf(r2 * (-1.f / 32.f)) * inv11sq;
      if (dy >= 13 && dy <= 17 && dx >= 13 && dx <= 17)
        v += expf(r2 * (-1.f / 8.f)) * inv5sq;
      s_stamp[idx] = v;
    }
  }
  if (t < 128) {
    s_wx[t] = wgx[n * 1024 + p0 + t];
    s_wy[t] = wgy[n * 1024 + p0 + t];
    s_vis[t] = visg[n * 1024 + p0 + t];
  }
  if (t < 64) {
    s_kpx[t] = kp1[(k0 + t) * 4 + 3];
    s_kpy[t] = kp1[(k0 + t) * 4 + 2];
    s_cnt[t] = cntw[n * 1024 + k0 + t];
  }
#pragma unroll
  for (int i = t; i < 512; i += 256) s_cells[i] = cellw[(n * 1024 + k0) * 8 + i];
  __syncthreads();

  // ---- MFMA: 4 waves x 16 kp rows x 8 px tiles, K=128 in 4 steps ----
  const int w = t >> 6;
  const int l = t & 63;
  const int arow = (w << 4) + (l & 15);
  short8 af[4];
#pragma unroll
  for (int ks = 0; ks < 4; ++ks) {
    int oct = (l >> 4) + 4 * ks;
    af[ks] = *(const short8*)((const char*)sA + arow * 256 +
                              ((oct * 16) ^ ((arow & 7) << 4)));
  }
  f32x4v acc[8];
#pragma unroll
  for (int nt = 0; nt < 8; ++nt) acc[nt] = (f32x4v){0.f, 0.f, 0.f, 0.f};
#pragma unroll
  for (int nt = 0; nt < 8; ++nt) {
    int pxl = nt * 16 + (l & 15);
    int pbase = pxl * 256;
    int psw = (pxl & 7) << 4;
#pragma unroll
    for (int ks = 0; ks < 4; ++ks) {
      int oct = (l >> 4) + 4 * ks;
      short8 bf = *(const short8*)((const char*)sB + pbase + ((oct * 16) ^ psw));
      acc[nt] = __builtin_amdgcn_mfma_f32_16x16x32_bf16(af[ks], bf, acc[nt], 0, 0, 0);
    }
  }

  // ---- epilogue: s, ns (stamp lookups), hinge, reduce ----
  const float POSL = 112.30770111083984f;  // 374.359 * 0.3
  const int lrow = ((l >> 4) << 2);
  float lp = 0.f;
#pragma unroll
  for (int nt = 0; nt < 8; ++nt) {
    int pxl = nt * 16 + (l & 15);
    int pxg = p0 + pxl;
    int ph = pxg >> 5, pw = pxg & 31;
    float wx_ = s_wx[pxl], wy_ = s_wy[pxl], vv = s_vis[pxl];
#pragma unroll
    for (int r = 0; r < 4; ++r) {
      int kp = (w << 4) + lrow + r;
      float dx = s_kpx[kp] - wx_;
      float dy = s_kpy[kp] - wy_;
      float d2 = dx * dx + dy * dy;
      float sval = (d2 <= 56.25f) ? 1.f : 0.f;
      float blur = 0.f;
      int cn = s_cnt[kp];
      for (int j = 0; j < cn; ++j) {
        int cell = s_cells[kp * 8 + j];
        int dyi = ph - (cell >> 5) + 15;
        int dxi = pw - (cell & 31) + 15;
        if ((unsigned)dyi < 31u && (unsigned)dxi < 31u)
          blur += s_stamp[dyi * 31 + dxi];
      }
      float dot = acc[nt][r];
      float pos = fmaxf(1.f - dot, 0.f);
      float neg = fmaxf(dot - 0.2f, 0.f);
      lp = fmaf(POSL * sval * vv, pos, lp);
      lp = fmaf((blur - 3.f * sval) * vv, neg, lp);
    }
  }
#pragma unroll
  for (int off = 32; off > 0; off >>= 1) lp += __shfl_down(lp, off, 64);
  if ((t & 63) == 0) s_red[t >> 6] = lp;
  __syncthreads();
  if (t == 0) {
    float tot = (s_red[0] + s_red[1]) + (s_red[2] + s_red[3]);
    atomicAdd(loss_out, tot * (float)(1.0 / (1024.0 * 374.359)));
  }
}

// ---------------------------------------------------------------------------
extern "C" void kernel_launch(void* const* d_in, const int* in_sizes, int n_in,
                              void* d_out, int out_size, void* d_ws, size_t ws_size,
                              hipStream_t stream) {
  (void)in_sizes; (void)n_in; (void)out_size; (void)ws_size;
  const float* kp1   = (const float*)d_in[0];
  const float* desc1 = (const float*)d_in[1];
  const float* desc2 = (const float*)d_in[2];
  const float* homo  = (const float*)d_in[3];
  const float* vism  = (const float*)d_in[4];
  float* out = (float*)d_out;

  float* visg = (float*)d_ws;          // 8192 f32
  float* wgx  = visg + 8192;           // 8192 f32
  float* wgy  = wgx + 8192;            // 8192 f32
  int*   cntw = (int*)(wgy + 8192);    // 8192 i32
  int*   cellw = cntw + 8192;          // 65536 i32  (total 384 KB)

  auto ksum = [](int ks, double sigma) {
    double sum = 0.0;
    for (int i = 0; i < ks; ++i) {
      double x = i - (ks - 1) / 2.0;
      sum += exp(-(x * x) / (2.0 * sigma * sigma));
    }
    return sum;
  };
  double s31 = ksum(31, 7.0), s11 = ksum(11, 4.0), s5 = ksum(5, 2.0);
  float inv31sq = (float)(1.0 / (s31 * s31));
  float inv11sq = (float)(1.0 / (s11 * s11));
  float inv5sq  = (float)(1.0 / (s5 * s5));

  hipMemsetAsync(d_out, 0, sizeof(float), stream);  // zero loss accumulator
  prep_kernel<<<dim3(64), dim3(256), 0, stream>>>(vism, homo, visg, wgx, wgy);
  list_kernel<<<dim3(1024), dim3(256), 0, stream>>>(kp1, wgx, wgy, cntw, cellw);
  kpd_kernel<<<dim3(1024), dim3(128), 0, stream>>>(kp1, desc1, out + 1);
  main_kernel<<<dim3(1024), dim3(256), 0, stream>>>(
      kp1, desc2, visg, wgx, wgy, cntw, cellw, out + 1, out,
      inv31sq, inv11sq, inv5sq);
}

// Round 5
// 78.855 us; speedup vs baseline: 1.3077x; 1.3077x over previous
//
#include <hip/hip_runtime.h>
#include <math.h>

using short8 = __attribute__((ext_vector_type(8))) short;
using f32x4v = __attribute__((ext_vector_type(4))) float;

__device__ __forceinline__ short f2bf(float f) {  // fp32 -> bf16 RNE
  unsigned u = __builtin_bit_cast(unsigned, f);
  unsigned r = (u + 0x7fffu + ((u >> 16) & 1u)) >> 16;
  return (short)r;
}

// ---------------- fused prep: 4 roles by block range -----------------------
//  [0,64):    transpose desc2 [n][128c][1024px] fp32 -> d2t [n][1024px][128c] bf16
//  [64,128):  vis product over 8x8 patches -> visg [n][1024]
//  [128,640): kp1_desc bilinear (exact fp32 -> out, bf16 -> kpdb), 2 kp/block
//  [640,896): active-cell lists per (n, kp): cntw, cellw (32 kp/block)
__global__ __launch_bounds__(256) void prep_kernel(
    const float* __restrict__ kp1, const float* __restrict__ desc1,
    const float* __restrict__ desc2, const float* __restrict__ homo,
    const float* __restrict__ vism, float* __restrict__ okpd,
    float* __restrict__ visg, int* __restrict__ cntw, int* __restrict__ cellw,
    short* __restrict__ kpdb, short* __restrict__ d2t) {
  __shared__ short tile[128][132];
  __shared__ int cnt[32];
  __shared__ int cells[32][8];
  __shared__ float kx[32], ky[32];

  const int bid = blockIdx.x;
  const int t = threadIdx.x;

  if (bid < 64) {
    // ---- transpose + bf16 convert ----
    int n = bid & 7, pt = bid >> 3;
    int c = t >> 1, ph = (t & 1) * 64;
    const float4* src =
        (const float4*)(desc2 + ((size_t)n * 128 + c) * 1024 + pt * 128 + ph);
#pragma unroll
    for (int i = 0; i < 16; ++i) {
      float4 f = src[i];
      int px = ph + i * 4;
      tile[c][px] = f2bf(f.x);
      tile[c][px + 1] = f2bf(f.y);
      tile[c][px + 2] = f2bf(f.z);
      tile[c][px + 3] = f2bf(f.w);
    }
    __syncthreads();
    int px = t >> 1, ch = (t & 1) * 64;
    short* dst = d2t + ((size_t)n * 1024 + pt * 128 + px) * 128 + ch;
#pragma unroll
    for (int v = 0; v < 8; ++v) {
      short8 o;
#pragma unroll
      for (int j = 0; j < 8; ++j) o[j] = tile[ch + v * 8 + j][px];
      *(short8*)(dst + v * 8) = o;
    }
  } else if (bid < 128) {
    // ---- vis: 2 lanes per cell, 4 rows each ----
    int idx = bid - 64;
    int n = idx & 7, seg = idx >> 3;
    int cell = seg * 128 + (t >> 1);
    int ph = cell >> 5, pw = cell & 31;
    const float* mrow =
        vism + ((size_t)n * 256 + ph * 8 + (t & 1) * 4) * 256 + pw * 8;
    float v = 1.f;
#pragma unroll
    for (int dy = 0; dy < 4; ++dy) {
      const float4* p = (const float4*)(mrow + dy * 256);
      float4 a = p[0], b = p[1];
      v *= a.x * a.y * a.z * a.w;
      v *= b.x * b.y * b.z * b.w;
    }
    float pv = __shfl_xor(v, 1, 64);
    v *= pv;
    if ((t & 1) == 0) visg[n * 1024 + cell] = v;
  } else if (bid < 640) {
    // ---- kpd: bilinear, exact fp32 ----
    int k = (bid - 128) * 2 + (t >> 7);
    int c = t & 127;
    float b = kp1[k * 4 + 0];
    float y = kp1[k * 4 + 2] * 0.125f;
    float x = kp1[k * 4 + 3] * 0.125f;
    float x0 = fminf(fmaxf(floorf(x), 0.f), 31.f);
    float y0 = fminf(fmaxf(floorf(y), 0.f), 31.f);
    float x1 = fminf(x0 + 1.f, 31.f);
    float y1 = fminf(y0 + 1.f, 31.f);
    float wx = x - x0;
    float wy = y - y0;
    const float* dp = desc1 + ((size_t)(int)b * 128 + c) * 1024;
    int ix0 = (int)x0, ix1 = (int)x1, iy0 = (int)y0, iy1 = (int)y1;
    float d00 = dp[iy0 * 32 + ix0];
    float d01 = dp[iy0 * 32 + ix1];
    float d10 = dp[iy1 * 32 + ix0];
    float d11 = dp[iy1 * 32 + ix1];
    float r = d00 * (1.f - wx) * (1.f - wy) + d01 * wx * (1.f - wy)
            + d10 * (1.f - wx) * wy + d11 * wx * wy;
    okpd[k * 128 + c] = r;
    kpdb[k * 128 + c] = f2bf(r);
  } else {
    // ---- lists: 32 kp per block, scan all 1024 cells ----
    int idx = bid - 640;
    int n = idx & 7;
    int kp0 = (idx >> 3) * 32;
    if (t < 32) {
      cnt[t] = 0;
      kx[t] = kp1[(kp0 + t) * 4 + 3];
      ky[t] = kp1[(kp0 + t) * 4 + 2];
    }
    __syncthreads();
    const float h00 = homo[n * 9 + 0], h01 = homo[n * 9 + 1], h02 = homo[n * 9 + 2];
    const float h10 = homo[n * 9 + 3], h11 = homo[n * 9 + 4], h12 = homo[n * 9 + 5];
    const float h20 = homo[n * 9 + 6], h21 = homo[n * 9 + 7], h22 = homo[n * 9 + 8];
#pragma unroll
    for (int i = 0; i < 4; ++i) {
      int cell = t + 256 * i;
      int ph = cell >> 5, pw = cell & 31;
      float gx = (float)(pw * 8 + 4);
      float gy = (float)(ph * 8 + 4);
      float w0 = h00 * gx + h01 * gy + h02;
      float w1 = h10 * gx + h11 * gy + h12;
      float w2 = h20 * gx + h21 * gy + h22;
      float wx_ = w0 / w2, wy_ = w1 / w2;
#pragma unroll
      for (int kt = 0; kt < 32; ++kt) {
        float dx = kx[kt] - wx_;
        float dy = ky[kt] - wy_;
        if (dx * dx + dy * dy <= 56.25f) {
          int pos = atomicAdd(&cnt[kt], 1);
          if (pos < 8) cells[kt][pos] = cell;
        }
      }
    }
    __syncthreads();
    if (t < 32) cntw[n * 1024 + kp0 + t] = min(cnt[t], 8);
    cellw[(size_t)(n * 1024 + kp0) * 8 + t] = cells[t >> 3][t & 7];
  }
}

// ---------------- main: MFMA GEMM (frags direct from global) + epilogue -----
// block = (n, kp-tile 64, px-tile 128); 4 waves x 16 kp x 128 px each.
__global__ __launch_bounds__(256, 4) void main_kernel(
    const float* __restrict__ kp1, const float* __restrict__ homo,
    const float* __restrict__ visg, const int* __restrict__ cntw,
    const int* __restrict__ cellw, const short* __restrict__ kpdb,
    const short* __restrict__ d2t, float* __restrict__ loss_out,
    float inv31sq, float inv11sq, float inv5sq) {
  __shared__ float s_stamp[961];
  __shared__ float s_wx[128], s_wy[128], s_vis[128];
  __shared__ float s_kpx[64], s_kpy[64];
  __shared__ int s_cnt[64];
  __shared__ int s_cells[512];
  __shared__ float s_red[4];

  const int t = threadIdx.x;
  const int bid = blockIdx.x;
  const int n = bid & 7;               // XCD-locality swizzle
  const int rem = bid >> 3;
  const int k0 = (rem & 15) * 64;
  const int p0 = (rem >> 4) * 128;

  // ---- prologue: stamp table + tile metadata ----
#pragma unroll
  for (int j = 0; j < 4; ++j) {
    int idx = t + 256 * j;
    if (idx < 961) {
      int dy = idx / 31, dx = idx % 31;
      float ay = (float)(dy - 15), ax = (float)(dx - 15);
      float r2 = ay * ay + ax * ax;
      float v = expf(r2 * (-1.f / 98.f)) * inv31sq;
      if (dy >= 10 && dy <= 20 && dx >= 10 && dx <= 20)
        v += expf(r2 * (-1.f / 32.f)) * inv11sq;
      if (dy >= 13 && dy <= 17 && dx >= 13 && dx <= 17)
        v += expf(r2 * (-1.f / 8.f)) * inv5sq;
      s_stamp[idx] = v;
    }
  }
  if (t < 128) {
    int pxg = p0 + t;
    int ph = pxg >> 5, pw = pxg & 31;
    float gx = (float)(pw * 8 + 4);
    float gy = (float)(ph * 8 + 4);
    float w0 = homo[n * 9 + 0] * gx + homo[n * 9 + 1] * gy + homo[n * 9 + 2];
    float w1 = homo[n * 9 + 3] * gx + homo[n * 9 + 4] * gy + homo[n * 9 + 5];
    float w2 = homo[n * 9 + 6] * gx + homo[n * 9 + 7] * gy + homo[n * 9 + 8];
    s_wx[t] = w0 / w2;
    s_wy[t] = w1 / w2;
    s_vis[t] = visg[n * 1024 + pxg];
  }
  if (t < 64) {
    s_kpx[t] = kp1[(k0 + t) * 4 + 3];
    s_kpy[t] = kp1[(k0 + t) * 4 + 2];
    s_cnt[t] = cntw[n * 1024 + k0 + t];
  }
  s_cells[t] = cellw[(size_t)(n * 1024 + k0) * 8 + t];
  s_cells[t + 256] = cellw[(size_t)(n * 1024 + k0) * 8 + t + 256];
  __syncthreads();

  // ---- MFMA: fragments straight from global (L1/L2-resident bf16) ----
  const int w = t >> 6, l = t & 63;
  const int lr = l & 15, lh = l >> 4;
  const short* Abase = kpdb + (size_t)(k0 + (w << 4) + lr) * 128 + lh * 8;
  short8 af[4];
#pragma unroll
  for (int ks = 0; ks < 4; ++ks) af[ks] = *(const short8*)(Abase + ks * 32);
  const short* Bbase = d2t + ((size_t)n * 1024 + p0 + lr) * 128 + lh * 8;
  f32x4v acc[8];
#pragma unroll
  for (int nt = 0; nt < 8; ++nt) {
    acc[nt] = (f32x4v){0.f, 0.f, 0.f, 0.f};
    const short* bp = Bbase + nt * 16 * 128;
#pragma unroll
    for (int ks = 0; ks < 4; ++ks) {
      short8 bf = *(const short8*)(bp + ks * 32);
      acc[nt] =
          __builtin_amdgcn_mfma_f32_16x16x32_bf16(af[ks], bf, acc[nt], 0, 0, 0);
    }
  }

  // ---- epilogue: s, ns (sparse stamp lookups), hinge, reduce ----
  const float POSL = 112.30770111083984f;  // 374.359 * 0.3
  const int lrow = lh << 2;
  float lp = 0.f;
#pragma unroll
  for (int nt = 0; nt < 8; ++nt) {
    int pxl = nt * 16 + lr;
    int pxg = p0 + pxl;
    int ph = pxg >> 5, pw = pxg & 31;
    float wx_ = s_wx[pxl], wy_ = s_wy[pxl], vv = s_vis[pxl];
#pragma unroll
    for (int r = 0; r < 4; ++r) {
      int kp = (w << 4) + lrow + r;
      float dx = s_kpx[kp] - wx_;
      float dy = s_kpy[kp] - wy_;
      float d2 = dx * dx + dy * dy;
      float sval = (d2 <= 56.25f) ? 1.f : 0.f;
      float blur = 0.f;
      int cn = s_cnt[kp];
      for (int j = 0; j < cn; ++j) {
        int cell = s_cells[kp * 8 + j];
        int dyi = ph - (cell >> 5) + 15;
        int dxi = pw - (cell & 31) + 15;
        if ((unsigned)dyi < 31u && (unsigned)dxi < 31u)
          blur += s_stamp[dyi * 31 + dxi];
      }
      float dot = acc[nt][r];
      float pos = fmaxf(1.f - dot, 0.f);
      float neg = fmaxf(dot - 0.2f, 0.f);
      lp = fmaf(POSL * sval * vv, pos, lp);
      lp = fmaf((blur - 3.f * sval) * vv, neg, lp);
    }
  }
#pragma unroll
  for (int off = 32; off > 0; off >>= 1) lp += __shfl_down(lp, off, 64);
  if ((t & 63) == 0) s_red[t >> 6] = lp;
  __syncthreads();
  if (t == 0) {
    float tot = (s_red[0] + s_red[1]) + (s_red[2] + s_red[3]);
    atomicAdd(loss_out, tot * (float)(1.0 / (1024.0 * 374.359)));
  }
}

// ---------------------------------------------------------------------------
extern "C" void kernel_launch(void* const* d_in, const int* in_sizes, int n_in,
                              void* d_out, int out_size, void* d_ws, size_t ws_size,
                              hipStream_t stream) {
  (void)in_sizes; (void)n_in; (void)out_size; (void)ws_size;
  const float* kp1   = (const float*)d_in[0];
  const float* desc1 = (const float*)d_in[1];
  const float* desc2 = (const float*)d_in[2];
  const float* homo  = (const float*)d_in[3];
  const float* vism  = (const float*)d_in[4];
  float* out = (float*)d_out;

  float* visg  = (float*)d_ws;            // 8192 f32   (32 KB)
  int*   cntw  = (int*)(visg + 8192);     // 8192 i32   (32 KB)
  int*   cellw = cntw + 8192;             // 65536 i32  (256 KB)
  short* kpdb  = (short*)(cellw + 65536); // 131072 bf16 (256 KB)
  short* d2t   = kpdb + 131072;           // 1048576 bf16 (2 MB)

  auto ksum = [](int ks, double sigma) {
    double sum = 0.0;
    for (int i = 0; i < ks; ++i) {
      double x = i - (ks - 1) / 2.0;
      sum += exp(-(x * x) / (2.0 * sigma * sigma));
    }
    return sum;
  };
  double s31 = ksum(31, 7.0), s11 = ksum(11, 4.0), s5 = ksum(5, 2.0);
  float inv31sq = (float)(1.0 / (s31 * s31));
  float inv11sq = (float)(1.0 / (s11 * s11));
  float inv5sq  = (float)(1.0 / (s5 * s5));

  hipMemsetAsync(d_out, 0, sizeof(float), stream);  // zero loss accumulator
  prep_kernel<<<dim3(896), dim3(256), 0, stream>>>(
      kp1, desc1, desc2, homo, vism, out + 1, visg, cntw, cellw, kpdb, d2t);
  main_kernel<<<dim3(1024), dim3(256), 0, stream>>>(
      kp1, homo, visg, cntw, cellw, kpdb, d2t, out, inv31sq, inv11sq, inv5sq);
}

// Round 6
// 44.274 us; speedup vs baseline: 2.3292x; 1.7811x over previous
//
#include <hip/hip_runtime.h>
#include <math.h>

using short8 = __attribute__((ext_vector_type(8))) short;
using f32x4v = __attribute__((ext_vector_type(4))) float;

__device__ __forceinline__ short f2bf(float f) {  // fp32 -> bf16 RNE
  unsigned u = __builtin_bit_cast(unsigned, f);
  unsigned r = (u + 0x7fffu + ((u >> 16) & 1u)) >> 16;
  return (short)r;
}

// ---------------- fused prep: 4 roles by block range -----------------------
//  [0,256):     transpose desc2 -> d2t [n][1024px][128c] bf16 (32 px/block)
//  [256,320):   vis product over 8x8 patches -> visg [n][1024]
//  [320,832):   kp1_desc bilinear (fp32 -> out, bf16 -> kpdb), 2 kp/block
//  [832,1088):  active-cell lists per (n, kp): cntw, cellw (32 kp/block)
__global__ __launch_bounds__(256) void prep_kernel(
    const float* __restrict__ kp1, const float* __restrict__ desc1,
    const float* __restrict__ desc2, const float* __restrict__ homo,
    const float* __restrict__ vism, float* __restrict__ okpd,
    float* __restrict__ visg, int* __restrict__ cntw, int* __restrict__ cellw,
    short* __restrict__ kpdb, short* __restrict__ d2t) {
  __shared__ short tile[128][33];
  __shared__ int cnt[32];
  __shared__ int cells[32][8];
  __shared__ float kx[32], ky[32];

  const int bid = blockIdx.x;
  const int t = threadIdx.x;

  if (bid < 256) {
    // ---- transpose + bf16: block = (n, 32-px strip), 128 c ----
    int n = bid & 7, q = bid >> 3;          // q in [0,32): px strip base q*32
#pragma unroll
    for (int pass = 0; pass < 4; ++pass) {
      int c = pass * 32 + (t >> 3);
      int px4 = (t & 7) * 4;                 // 8 lanes x 16B = 32 px contiguous
      const float4* src = (const float4*)(desc2 + ((size_t)n * 128 + c) * 1024 +
                                          q * 32 + px4);
      float4 f = *src;
      tile[c][px4] = f2bf(f.x);
      tile[c][px4 + 1] = f2bf(f.y);
      tile[c][px4 + 2] = f2bf(f.z);
      tile[c][px4 + 3] = f2bf(f.w);
    }
    __syncthreads();
#pragma unroll
    for (int pass = 0; pass < 2; ++pass) {
      int px = pass * 16 + (t >> 4);
      int ch = (t & 15) * 8;                 // 16 lanes x 16B = 128 c contiguous
      short8 o;
#pragma unroll
      for (int j = 0; j < 8; ++j) o[j] = tile[ch + j][px];
      *(short8*)(d2t + ((size_t)n * 1024 + q * 32 + px) * 128 + ch) = o;
    }
  } else if (bid < 320) {
    // ---- vis: 2 lanes per cell, 4 rows each ----
    int idx = bid - 256;
    int n = idx & 7, seg = idx >> 3;
    int cell = seg * 128 + (t >> 1);
    int ph = cell >> 5, pw = cell & 31;
    const float* mrow =
        vism + ((size_t)n * 256 + ph * 8 + (t & 1) * 4) * 256 + pw * 8;
    float v = 1.f;
#pragma unroll
    for (int dy = 0; dy < 4; ++dy) {
      const float4* p = (const float4*)(mrow + dy * 256);
      float4 a = p[0], b = p[1];
      v *= a.x * a.y * a.z * a.w;
      v *= b.x * b.y * b.z * b.w;
    }
    float pv = __shfl_xor(v, 1, 64);
    v *= pv;
    if ((t & 1) == 0) visg[n * 1024 + cell] = v;
  } else if (bid < 832) {
    // ---- kpd: bilinear, exact fp32 ----
    int k = (bid - 320) * 2 + (t >> 7);
    int c = t & 127;
    float b = kp1[k * 4 + 0];
    float y = kp1[k * 4 + 2] * 0.125f;
    float x = kp1[k * 4 + 3] * 0.125f;
    float x0 = fminf(fmaxf(floorf(x), 0.f), 31.f);
    float y0 = fminf(fmaxf(floorf(y), 0.f), 31.f);
    float x1 = fminf(x0 + 1.f, 31.f);
    float y1 = fminf(y0 + 1.f, 31.f);
    float wx = x - x0;
    float wy = y - y0;
    const float* dp = desc1 + ((size_t)(int)b * 128 + c) * 1024;
    int ix0 = (int)x0, ix1 = (int)x1, iy0 = (int)y0, iy1 = (int)y1;
    float d00 = dp[iy0 * 32 + ix0];
    float d01 = dp[iy0 * 32 + ix1];
    float d10 = dp[iy1 * 32 + ix0];
    float d11 = dp[iy1 * 32 + ix1];
    float r = d00 * (1.f - wx) * (1.f - wy) + d01 * wx * (1.f - wy)
            + d10 * (1.f - wx) * wy + d11 * wx * wy;
    okpd[k * 128 + c] = r;
    kpdb[k * 128 + c] = f2bf(r);
  } else {
    // ---- lists: 32 kp per block, scan all 1024 cells ----
    int idx = bid - 832;
    int n = idx & 7;
    int kp0 = (idx >> 3) * 32;
    if (t < 32) {
      cnt[t] = 0;
      kx[t] = kp1[(kp0 + t) * 4 + 3];
      ky[t] = kp1[(kp0 + t) * 4 + 2];
    }
    __syncthreads();
    const float h00 = homo[n * 9 + 0], h01 = homo[n * 9 + 1], h02 = homo[n * 9 + 2];
    const float h10 = homo[n * 9 + 3], h11 = homo[n * 9 + 4], h12 = homo[n * 9 + 5];
    const float h20 = homo[n * 9 + 6], h21 = homo[n * 9 + 7], h22 = homo[n * 9 + 8];
#pragma unroll
    for (int i = 0; i < 4; ++i) {
      int cell = t + 256 * i;
      int ph = cell >> 5, pw = cell & 31;
      float gx = (float)(pw * 8 + 4);
      float gy = (float)(ph * 8 + 4);
      float w0 = h00 * gx + h01 * gy + h02;
      float w1 = h10 * gx + h11 * gy + h12;
      float w2 = h20 * gx + h21 * gy + h22;
      float wx_ = w0 / w2, wy_ = w1 / w2;
#pragma unroll
      for (int kt = 0; kt < 32; ++kt) {
        float dx = kx[kt] - wx_;
        float dy = ky[kt] - wy_;
        if (dx * dx + dy * dy <= 56.25f) {
          int pos = atomicAdd(&cnt[kt], 1);
          if (pos < 8) cells[kt][pos] = cell;
        }
      }
    }
    __syncthreads();
    if (t < 32) cntw[n * 1024 + kp0 + t] = min(cnt[t], 8);
    cellw[(size_t)(n * 1024 + kp0) * 8 + t] = cells[t >> 3][t & 7];
  }
}

// ---------------- main: MFMA GEMM + branch-free blur + hinge ---------------
// block = (n, kp-tile 64, px-tile 128); 4 waves x 16 kp x 128 px each.
__global__ __launch_bounds__(256, 4) void main_kernel(
    const float* __restrict__ kp1, const float* __restrict__ homo,
    const float* __restrict__ visg, const int* __restrict__ cntw,
    const int* __restrict__ cellw, const short* __restrict__ kpdb,
    const short* __restrict__ d2t, float* __restrict__ part,
    float inv31sq, float inv11sq, float inv5sq) {
  __shared__ float s_T[63 * 64];    // padded stamp: T[yy][xx]=g(yy-31,xx-31)
  __shared__ float s_wx[128], s_wy[128], s_vis[128];
  __shared__ float s_kpx[64], s_kpy[64];
  __shared__ int s_cnt[64];
  __shared__ int s_cells[512];
  __shared__ float s_red[4];

  const int t = threadIdx.x;
  const int bid = blockIdx.x;
  const int n = bid & 7;               // XCD-locality swizzle
  const int rem = bid >> 3;
  const int k0 = (rem & 15) * 64;
  const int p0 = (rem >> 4) * 128;

  // ---- prologue: zeroed padded stamp table + fill 31x31 core ----
#pragma unroll
  for (int i = t; i < 63 * 64; i += 256) s_T[i] = 0.f;
  __syncthreads();   // (cheap; ensures zeros before core fill writes race-free)
#pragma unroll
  for (int j = 0; j < 4; ++j) {
    int idx = t + 256 * j;
    if (idx < 961) {
      int dy = idx / 31, dx = idx % 31;
      float ay = (float)(dy - 15), ax = (float)(dx - 15);
      float r2 = ay * ay + ax * ax;
      float v = expf(r2 * (-1.f / 98.f)) * inv31sq;
      if (dy >= 10 && dy <= 20 && dx >= 10 && dx <= 20)
        v += expf(r2 * (-1.f / 32.f)) * inv11sq;
      if (dy >= 13 && dy <= 17 && dx >= 13 && dx <= 17)
        v += expf(r2 * (-1.f / 8.f)) * inv5sq;
      s_T[(dy + 16) * 64 + (dx + 16)] = v;
    }
  }
  if (t < 128) {
    int pxg = p0 + t;
    int ph = pxg >> 5, pw = pxg & 31;
    float gx = (float)(pw * 8 + 4);
    float gy = (float)(ph * 8 + 4);
    float w0 = homo[n * 9 + 0] * gx + homo[n * 9 + 1] * gy + homo[n * 9 + 2];
    float w1 = homo[n * 9 + 3] * gx + homo[n * 9 + 4] * gy + homo[n * 9 + 5];
    float w2 = homo[n * 9 + 6] * gx + homo[n * 9 + 7] * gy + homo[n * 9 + 8];
    s_wx[t] = w0 / w2;
    s_wy[t] = w1 / w2;
    s_vis[t] = visg[n * 1024 + pxg];
  }
  if (t < 64) {
    s_kpx[t] = kp1[(k0 + t) * 4 + 3];
    s_kpy[t] = kp1[(k0 + t) * 4 + 2];
    s_cnt[t] = cntw[n * 1024 + k0 + t];
  }
  s_cells[t] = cellw[(size_t)(n * 1024 + k0) * 8 + t];
  s_cells[t + 256] = cellw[(size_t)(n * 1024 + k0) * 8 + t + 256];
  __syncthreads();

  // ---- MFMA: fragments straight from global (L2-resident bf16) ----
  const int w = t >> 6, l = t & 63;
  const int lr = l & 15, lh = l >> 4;
  const short* Abase = kpdb + (size_t)(k0 + (w << 4) + lr) * 128 + lh * 8;
  short8 af[4];
#pragma unroll
  for (int ks = 0; ks < 4; ++ks) af[ks] = *(const short8*)(Abase + ks * 32);
  const short* Bbase = d2t + ((size_t)n * 1024 + p0 + lr) * 128 + lh * 8;
  f32x4v acc[8];
#pragma unroll
  for (int nt = 0; nt < 8; ++nt) {
    acc[nt] = (f32x4v){0.f, 0.f, 0.f, 0.f};
    const short* bp = Bbase + nt * 16 * 128;
#pragma unroll
    for (int ks = 0; ks < 4; ++ks) {
      short8 bf = *(const short8*)(bp + ks * 32);
      acc[nt] =
          __builtin_amdgcn_mfma_f32_16x16x32_bf16(af[ks], bf, acc[nt], 0, 0, 0);
    }
  }

  // ---- blur: cell-outer, unrolled px-inner, branch-free table lookups ----
  // thread's pixels: pxl = nt*16+lr -> ph = ph0 + (nt>>1), pw = (nt&1)*16 + lr
  const int ph0 = p0 >> 5;
  float blur[8][4];
#pragma unroll
  for (int nt = 0; nt < 8; ++nt)
#pragma unroll
    for (int r = 0; r < 4; ++r) blur[nt][r] = 0.f;
#pragma unroll
  for (int r = 0; r < 4; ++r) {
    int kp = (w << 4) + (lh << 2) + r;
    int cn = s_cnt[kp];
    for (int j = 0; j < cn; ++j) {      // <=4 iters (disk covers <=4 cells)
      int cell = s_cells[kp * 8 + j];
      int ybase = ph0 - (cell >> 5) + 31;
      int xbase = lr - (cell & 31) + 31;
#pragma unroll
      for (int nt = 0; nt < 8; ++nt)
        blur[nt][r] += s_T[(ybase + (nt >> 1)) * 64 + xbase + (nt & 1) * 16];
    }
  }

  // ---- hinge + reduce ----
  const float POSL = 112.30770111083984f;  // 374.359 * 0.3
  float lp = 0.f;
#pragma unroll
  for (int nt = 0; nt < 8; ++nt) {
    int pxl = nt * 16 + lr;
    float wx_ = s_wx[pxl], wy_ = s_wy[pxl], vv = s_vis[pxl];
#pragma unroll
    for (int r = 0; r < 4; ++r) {
      int kp = (w << 4) + (lh << 2) + r;
      float dx = s_kpx[kp] - wx_;
      float dy = s_kpy[kp] - wy_;
      float sval = (dx * dx + dy * dy <= 56.25f) ? 1.f : 0.f;
      float dot = acc[nt][r];
      float pos = fmaxf(1.f - dot, 0.f);
      float neg = fmaxf(dot - 0.2f, 0.f);
      lp = fmaf(POSL * sval * vv, pos, lp);
      lp = fmaf((blur[nt][r] - 3.f * sval) * vv, neg, lp);
    }
  }
#pragma unroll
  for (int off = 32; off > 0; off >>= 1) lp += __shfl_down(lp, off, 64);
  if ((t & 63) == 0) s_red[t >> 6] = lp;
  __syncthreads();
  if (t == 0)
    part[bid] = (s_red[0] + s_red[1]) + (s_red[2] + s_red[3]);
}

// ---------------- final: sum 1024 partials -> loss -------------------------
__global__ void reduce_kernel(const float* __restrict__ part,
                              float* __restrict__ out) {
  __shared__ float s_red[4];
  int t = threadIdx.x;
  float v = part[t] + part[t + 256] + part[t + 512] + part[t + 768];
#pragma unroll
  for (int off = 32; off > 0; off >>= 1) v += __shfl_down(v, off, 64);
  if ((t & 63) == 0) s_red[t >> 6] = v;
  __syncthreads();
  if (t == 0)
    out[0] = ((s_red[0] + s_red[1]) + (s_red[2] + s_red[3])) *
             (float)(1.0 / (1024.0 * 374.359));
}

// ---------------------------------------------------------------------------
extern "C" void kernel_launch(void* const* d_in, const int* in_sizes, int n_in,
                              void* d_out, int out_size, void* d_ws, size_t ws_size,
                              hipStream_t stream) {
  (void)in_sizes; (void)n_in; (void)out_size; (void)ws_size;
  const float* kp1   = (const float*)d_in[0];
  const float* desc1 = (const float*)d_in[1];
  const float* desc2 = (const float*)d_in[2];
  const float* homo  = (const float*)d_in[3];
  const float* vism  = (const float*)d_in[4];
  float* out = (float*)d_out;

  float* visg  = (float*)d_ws;            // 8192 f32    (32 KB)
  int*   cntw  = (int*)(visg + 8192);     // 8192 i32    (32 KB)
  int*   cellw = cntw + 8192;             // 65536 i32   (256 KB)
  short* kpdb  = (short*)(cellw + 65536); // 131072 bf16 (256 KB)
  short* d2t   = kpdb + 131072;           // 1048576 bf16 (2 MB)
  float* part  = (float*)(d2t + 1048576); // 1024 f32    (4 KB)

  auto ksum = [](int ks, double sigma) {
    double sum = 0.0;
    for (int i = 0; i < ks; ++i) {
      double x = i - (ks - 1) / 2.0;
      sum += exp(-(x * x) / (2.0 * sigma * sigma));
    }
    return sum;
  };
  double s31 = ksum(31, 7.0), s11 = ksum(11, 4.0), s5 = ksum(5, 2.0);
  float inv31sq = (float)(1.0 / (s31 * s31));
  float inv11sq = (float)(1.0 / (s11 * s11));
  float inv5sq  = (float)(1.0 / (s5 * s5));

  prep_kernel<<<dim3(1088), dim3(256), 0, stream>>>(
      kp1, desc1, desc2, homo, vism, out + 1, visg, cntw, cellw, kpdb, d2t);
  main_kernel<<<dim3(1024), dim3(256), 0, stream>>>(
      kp1, homo, visg, cntw, cellw, kpdb, d2t, part,
      inv31sq, inv11sq, inv5sq);
  reduce_kernel<<<dim3(1), dim3(256), 0, stream>>>(part, out);
}